// Round 1
// baseline (776.731 us; speedup 1.0000x reference)
//
#include <hip/hip_runtime.h>

#define BROWS 131072

typedef __attribute__((ext_vector_type(8))) __bf16 bf16x8;
typedef __attribute__((ext_vector_type(4))) __bf16 bf16x4;
typedef __attribute__((ext_vector_type(4))) float f32x4;

__device__ __forceinline__ float sigmoidf_(float x) {
    return 1.0f / (1.0f + __expf(-x));
}
__device__ __forceinline__ float tanhf_(float x) {
    return 1.0f - 2.0f / (__expf(2.0f * x) + 1.0f);
}

// ---------------------------------------------------------------------------
// Kernel 1: transpose W_gates rows 3..258 (the h part) into bf16 WT[1024][256]
// (B^T layout: WT[col][k] = W_gates[3+k][col]) so MFMA B-frags load like A-frags.
// ---------------------------------------------------------------------------
__global__ void wt_kernel(const float* __restrict__ Wg, __bf16* __restrict__ WT) {
    int gid = blockIdx.x * 256 + threadIdx.x;   // 0 .. 262143
    int k = gid >> 10;                           // 0..255
    int c = gid & 1023;                          // 0..1023
    float v = Wg[(3 + k) * 1024 + c];            // coalesced over c
    WT[c * 256 + k] = (__bf16)v;                 // scattered 2B writes (L2)
}

// ---------------------------------------------------------------------------
// Kernel 2: switch counts. One wave per row-iteration; lane l covers h cols
// 4l..4l+3 (float4 coalesced), lanes 0..2 also cover the 3 input cols.
// sigmoid(x) > 0.5  <=>  logit > 0.
// ---------------------------------------------------------------------------
__global__ void switch_kernel(const float* __restrict__ x, const float* __restrict__ h,
                              const float* __restrict__ Wsw, const float* __restrict__ bsw,
                              int* __restrict__ cnt) {
    const int lane = threadIdx.x & 63;
    const int gw = (blockIdx.x * blockDim.x + threadIdx.x) >> 6;
    const int nw = (gridDim.x * blockDim.x) >> 6;

    float w0[4], w1[4];
#pragma unroll
    for (int j = 0; j < 4; ++j) {
        int r = 3 + 4 * lane + j;                // W_switch row for h col 4l+j
        w0[j] = Wsw[r * 2 + 0];
        w1[j] = Wsw[r * 2 + 1];
    }
    float wi0 = 0.0f, wi1 = 0.0f;
    if (lane < 3) { wi0 = Wsw[lane * 2 + 0]; wi1 = Wsw[lane * 2 + 1]; }
    const float b0 = bsw[0], b1 = bsw[1];

    int ci = 0, cg = 0;
    for (int row = gw; row < BROWS; row += nw) {
        const float4 hv = *(const float4*)(h + row * 256 + 4 * lane);
        float si = hv.x * w0[0] + hv.y * w0[1] + hv.z * w0[2] + hv.w * w0[3];
        float sg = hv.x * w1[0] + hv.y * w1[1] + hv.z * w1[2] + hv.w * w1[3];
        if (lane < 3) {
            float xv = x[row * 3 + lane];
            si += xv * wi0;
            sg += xv * wi1;
        }
#pragma unroll
        for (int off = 32; off >= 1; off >>= 1) {
            si += __shfl_xor(si, off, 64);
            sg += __shfl_xor(sg, off, 64);
        }
        if (lane == 0) {
            ci += (si + b0) > 0.0f;
            cg += (sg + b1) > 0.0f;
        }
    }
    if (lane == 0) {
        atomicAdd(&cnt[0], ci);
        atomicAdd(&cnt[1], cg);
    }
}

// ---------------------------------------------------------------------------
// Kernel 3: main GEMM + LSTM epilogue.
// Block: 256 threads = 4 waves, tile = 128 rows x 32 h-cols (=128 gate cols).
// Wave (w>>1) picks row half (0/64), (w&1) picks 16-h-col half.
// Each wave: 4 m-tiles x 4 n-tiles of 16x16; n-tile nt == gate nt (i,f,g,o)
// at the SAME h-cols, so the epilogue is fully in-register per lane.
// Accumulator init = bias + input(3 cols) rank-3 update; MFMA K = 256 (h only).
// ---------------------------------------------------------------------------
__global__ __launch_bounds__(256)
void lstm_main(const float* __restrict__ x,      // B x 3
               const float* __restrict__ h,      // B x 256
               const float* __restrict__ c_cur,  // B x 256
               const float* __restrict__ Wg,     // 259 x 1024 (fp32)
               const float* __restrict__ bg,     // 1024
               const __bf16* __restrict__ WT,    // 1024 x 256 bf16 (B^T)
               const int* __restrict__ cnt,
               float* __restrict__ out) {
    __shared__ __bf16 A_lds[128 * 40];           // pitch 40 bf16 = 80 B

    const int tid = threadIdx.x;
    const int lane = tid & 63;
    const int w = tid >> 6;
    const int q = lane >> 4;
    const int ln = lane & 15;
    const int m0 = blockIdx.y * 128;
    const int j0 = blockIdx.x * 32;
    const int wrow = (w >> 1) * 64;
    const int colh = j0 + (w & 1) * 16 + ln;     // h column 0..255

    const int ci = cnt[0], cg = cnt[1];          // thr = B*0.5 = 65536 exactly
    const bool cond_i = (cg < 65536) && (ci > 65536);
    const bool cond_g = (cg > 65536) && (ci < 65536);

    // ---- accumulator init: bias + input @ W_gates[0:3] ----
    f32x4 acc[4][4];
    float bcol[4], wx0[4], wx1[4], wx2[4];
#pragma unroll
    for (int nt = 0; nt < 4; ++nt) {
        int colg = nt * 256 + colh;
        bcol[nt] = bg[colg];
        wx0[nt] = Wg[0 * 1024 + colg];
        wx1[nt] = Wg[1 * 1024 + colg];
        wx2[nt] = Wg[2 * 1024 + colg];
    }
#pragma unroll
    for (int mt = 0; mt < 4; ++mt) {
#pragma unroll
        for (int r = 0; r < 4; ++r) {
            int row = m0 + wrow + mt * 16 + q * 4 + r;
            float x0 = x[row * 3 + 0];
            float x1 = x[row * 3 + 1];
            float x2 = x[row * 3 + 2];
#pragma unroll
            for (int nt = 0; nt < 4; ++nt) {
                acc[mt][nt][r] = bcol[nt] + x0 * wx0[nt] + x1 * wx1[nt] + x2 * wx2[nt];
            }
        }
    }

    // ---- K loop: 8 chunks of K=32 over h columns ----
    float4 areg[4];
#pragma unroll
    for (int i = 0; i < 4; ++i) {
        int idx = tid + 256 * i;
        int row = idx >> 3, kq = idx & 7;
        areg[i] = *(const float4*)(h + (m0 + row) * 256 + 0 * 32 + kq * 4);
    }

    const __bf16* wtb[4];
#pragma unroll
    for (int nt = 0; nt < 4; ++nt)
        wtb[nt] = WT + (nt * 256 + colh) * 256 + q * 8;

    for (int kc = 0; kc < 8; ++kc) {
        if (kc) __syncthreads();                 // protect LDS from prior readers
#pragma unroll
        for (int i = 0; i < 4; ++i) {
            int idx = tid + 256 * i;
            int row = idx >> 3, kq = idx & 7;
            bf16x4 v;
            v[0] = (__bf16)areg[i].x;
            v[1] = (__bf16)areg[i].y;
            v[2] = (__bf16)areg[i].z;
            v[3] = (__bf16)areg[i].w;
            *(bf16x4*)(&A_lds[row * 40 + kq * 4]) = v;
        }
        __syncthreads();
        if (kc < 7) {
#pragma unroll
            for (int i = 0; i < 4; ++i) {
                int idx = tid + 256 * i;
                int row = idx >> 3, kq = idx & 7;
                areg[i] = *(const float4*)(h + (m0 + row) * 256 + (kc + 1) * 32 + kq * 4);
            }
        }
        bf16x8 bfrag[4];
#pragma unroll
        for (int nt = 0; nt < 4; ++nt)
            bfrag[nt] = *(const bf16x8*)(wtb[nt] + kc * 32);
        bf16x8 afrag[4];
#pragma unroll
        for (int mt = 0; mt < 4; ++mt)
            afrag[mt] = *(const bf16x8*)(&A_lds[(wrow + mt * 16 + ln) * 40 + q * 8]);
#pragma unroll
        for (int mt = 0; mt < 4; ++mt)
#pragma unroll
            for (int nt = 0; nt < 4; ++nt)
                acc[mt][nt] = __builtin_amdgcn_mfma_f32_16x16x32_bf16(
                    afrag[mt], bfrag[nt], acc[mt][nt], 0, 0, 0);
    }

    // ---- epilogue: per lane, acc[mt][nt][r] = gate nt at (row, colh) ----
#pragma unroll
    for (int mt = 0; mt < 4; ++mt) {
#pragma unroll
        for (int r = 0; r < 4; ++r) {
            int row = m0 + wrow + mt * 16 + q * 4 + r;
            float gi = sigmoidf_(acc[mt][0][r]);
            float gf = sigmoidf_(acc[mt][1][r]);
            float gg = tanhf_(acc[mt][2][r]);
            float go = sigmoidf_(acc[mt][3][r]);
            float c = c_cur[row * 256 + colh];
            float X = cond_i ? gi : (cond_g ? gg : gi * gg);
            float cn = gf * c + X;
            float hn = go * tanhf_(cn);
            out[row * 256 + colh] = hn;
            out[BROWS * 256 + row * 256 + colh] = cn;
        }
    }
}

// ---------------------------------------------------------------------------
extern "C" void kernel_launch(void* const* d_in, const int* in_sizes, int n_in,
                              void* d_out, int out_size, void* d_ws, size_t ws_size,
                              hipStream_t stream) {
    const float* x   = (const float*)d_in[0];   // input_tensor B x 3
    const float* h   = (const float*)d_in[1];   // h_cur B x 256
    const float* c   = (const float*)d_in[2];   // c_cur B x 256
    const float* Wg  = (const float*)d_in[3];   // W_gates 259 x 1024
    const float* bg  = (const float*)d_in[4];   // b_gates 1024
    const float* Wsw = (const float*)d_in[5];   // W_switch 259 x 2
    const float* bsw = (const float*)d_in[6];   // b_switch 2
    float* out = (float*)d_out;

    int* cnt = (int*)d_ws;
    __bf16* WT = (__bf16*)((char*)d_ws + 1024);  // 1024*256*2 = 512 KB

    hipMemsetAsync(d_ws, 0, 8, stream);
    wt_kernel<<<1024, 256, 0, stream>>>(Wg, WT);
    switch_kernel<<<1024, 256, 0, stream>>>(x, h, Wsw, bsw, cnt);
    lstm_main<<<dim3(8, 1024), 256, 0, stream>>>(x, h, c, Wg, bg, WT, cnt, out);
}